// Round 2
// baseline (3957.911 us; speedup 1.0000x reference)
//
#include <hip/hip_runtime.h>
#include <hip/hip_bf16.h>

// ---------------------------------------------------------------------------
// PointAttentionEncoder1D: P=100k points, K=16 neighbors, channels 3->16->32,
// weight-process 32->64->32, softmax over channels, sum over K+1 rows.
// Round 2: inputs/weights/output are FLOAT32 (round-1 NaN proved buffers are
// f32, not bf16). Thread-per-(point,row); weights read directly from d_in at
// compile-time-uniform addresses -> s_load + SGPR operands for v_fma.
// ---------------------------------------------------------------------------

constexpr int PPB  = 15;   // points per block (15*17 = 255 active threads)
constexpr int ROWS = 17;   // K+1

__device__ __forceinline__ float lrelu(float v) { return v > 0.f ? v : 0.01f * v; }

// One 3->16->32 MLP with compile-time mlp index M (wave-uniform weight
// addresses -> scalar loads).
template <int M>
__device__ __forceinline__ void mlp_3_16_32(const float* __restrict__ mw1,
                                            const float* __restrict__ mb1,
                                            const float* __restrict__ mw2,
                                            const float* __restrict__ mb2,
                                            float a0, float a1, float a2,
                                            float* __restrict__ o) {
  const float* w1 = mw1 + M * 48;    // [3][16]
  const float* b1 = mb1 + M * 16;    // [16]
  const float* w2 = mw2 + M * 512;   // [16][32]
  const float* b2 = mb2 + M * 32;    // [32]
  float h[16];
#pragma unroll
  for (int j = 0; j < 16; j++)
    h[j] = lrelu(b1[j] + a0 * w1[j] + a1 * w1[16 + j] + a2 * w1[32 + j]);
#pragma unroll
  for (int c = 0; c < 32; c++) {
    float acc = b2[c];
#pragma unroll
    for (int j = 0; j < 16; j++) acc += h[j] * w2[j * 32 + c];
    o[c] = acc;
  }
}

__global__ __launch_bounds__(256) void point_attn_kernel(
    const float* __restrict__ center,   // [P][1][3]
    const float* __restrict__ other,    // [P][16][3]
    const float* __restrict__ mw1, const float* __restrict__ mb1,
    const float* __restrict__ mw2, const float* __restrict__ mb2,
    const float* __restrict__ ww1, const float* __restrict__ wb1,
    const float* __restrict__ ww2, const float* __restrict__ wb2,
    float* __restrict__ out, int P) {
  __shared__ float red[255 * 33];  // [thread][channel], stride 33: conflict-free

  const int t  = threadIdx.x;
  const int pt = t / ROWS;           // 0..14
  const int r  = t - pt * ROWS;      // 0..16
  const int p  = blockIdx.x * PPB + pt;
  const bool active = (t < PPB * ROWS) && (p < P);

  if (active) {
    const float c0 = center[(size_t)p * 3 + 0];
    const float c1 = center[(size_t)p * 3 + 1];
    const float c2 = center[(size_t)p * 3 + 2];
    float x0 = c0, x1 = c1, x2 = c2;
    if (r > 0) {
      const float* op = other + ((size_t)p * 16 + (r - 1)) * 3;
      x0 = op[0];
      x1 = op[1];
      x2 = op[2];
    }
    const float f0 = c0 - x0, f1 = c1 - x1, f2 = c2 - x2;  // fea_minus (0 for r==0)

    // pos = mlp5(fea_minus)
    float pos[32];
    mlp_3_16_32<5>(mw1, mb1, mw2, mb2, f0, f1, f2, pos);

    // v = (r==0 ? mlp2(center) : mlp4(x));  vp = v + pos
    float tA[32], tB[32], vp[32];
    mlp_3_16_32<2>(mw1, mb1, mw2, mb2, c0, c1, c2, tA);   // cv
    mlp_3_16_32<4>(mw1, mb1, mw2, mb2, x0, x1, x2, tB);   // ov
#pragma unroll
    for (int c = 0; c < 32; c++) vp[c] = (r == 0 ? tA[c] : tB[c]) + pos[c];

    // k = (r==0 ? mlp1(center) : mlp3(x))
    mlp_3_16_32<1>(mw1, mb1, mw2, mb2, c0, c1, c2, tA);   // ck
    mlp_3_16_32<3>(mw1, mb1, mw2, mb2, x0, x1, x2, tB);   // ok
#pragma unroll
    for (int c = 0; c < 32; c++) tA[c] = (r == 0 ? tA[c] : tB[c]);  // k

    // w = q - k + pos
    mlp_3_16_32<0>(mw1, mb1, mw2, mb2, c0, c1, c2, tB);   // q
    float w[32];
#pragma unroll
    for (int c = 0; c < 32; c++) w[c] = tB[c] - tA[c] + pos[c];

    // weight_process: 32 -> 64 (leaky) -> 32
    float h[64];
#pragma unroll
    for (int i = 0; i < 64; i++) h[i] = wb1[i];
#pragma unroll
    for (int c = 0; c < 32; c++) {
#pragma unroll
      for (int i = 0; i < 64; i++) h[i] += w[c] * ww1[c * 64 + i];
    }
#pragma unroll
    for (int i = 0; i < 64; i++) h[i] = lrelu(h[i]);
    float fw[32];
#pragma unroll
    for (int c = 0; c < 32; c++) {
      float acc = wb2[c];
#pragma unroll
      for (int i = 0; i < 64; i++) acc += h[i] * ww2[i * 32 + c];
      fw[c] = acc;
    }

    // softmax over channels (thread-local), times (v+pos)
    float m = fw[0];
#pragma unroll
    for (int c = 1; c < 32; c++) m = fmaxf(m, fw[c]);
    float s = 0.f;
#pragma unroll
    for (int c = 0; c < 32; c++) {
      fw[c] = __expf(fw[c] - m);
      s += fw[c];
    }
    const float inv = 1.f / s;
#pragma unroll
    for (int c = 0; c < 32; c++) red[t * 33 + c] = fw[c] * inv * vp[c];
  }

  __syncthreads();

  // reduce 17 rows per point, write output
  const int nval = min(PPB, P - blockIdx.x * PPB);
  for (int u = t; u < nval * 32; u += 256) {
    const int pp = u >> 5, c = u & 31;
    float s = 0.f;
#pragma unroll
    for (int rr = 0; rr < ROWS; rr++) s += red[(pp * ROWS + rr) * 33 + c];
    out[(size_t)(blockIdx.x * PPB + pp) * 32 + c] = s;
  }
}

extern "C" void kernel_launch(void* const* d_in, const int* in_sizes, int n_in,
                              void* d_out, int out_size, void* d_ws, size_t ws_size,
                              hipStream_t stream) {
  const float* center = (const float*)d_in[0];
  const float* other  = (const float*)d_in[1];
  const int P = in_sizes[0] / 3;
  const int blocks = (P + PPB - 1) / PPB;
  point_attn_kernel<<<blocks, 256, 0, stream>>>(
      center, other,
      (const float*)d_in[2], (const float*)d_in[3],
      (const float*)d_in[4], (const float*)d_in[5],
      (const float*)d_in[6], (const float*)d_in[7],
      (const float*)d_in[8], (const float*)d_in[9],
      (float*)d_out, P);
}

// Round 3
// 498.925 us; speedup vs baseline: 7.9329x; 7.9329x over previous
//
#include <hip/hip_runtime.h>
#include <hip/hip_bf16.h>

// ---------------------------------------------------------------------------
// PointAttentionEncoder1D: P=100k points, K=16 neighbors, channels 3->16->32,
// weight-process 32->64->32, softmax over channels, sum over K+1 rows.
// Round 3: FULLY UNIFORM control flow (no divergent branch around the math)
// so the compiler can turn all weight reads (uniform addresses, const
// __restrict__) into s_load_* on the scalar pipe. Weight inner loops
// reordered so reads are contiguous -> s_load_dwordx16.
// ---------------------------------------------------------------------------

constexpr int PPB  = 15;   // points per block (15*17 = 255 active threads)
constexpr int ROWS = 17;   // K+1

__device__ __forceinline__ float lrelu(float v) { return v > 0.f ? v : 0.01f * v; }

// One 3->16->32 MLP with compile-time mlp index M. All weight addresses are
// wave-uniform; j-outer/c-inner second layer keeps reads contiguous.
template <int M>
__device__ __forceinline__ void mlp_3_16_32(const float* __restrict__ mw1,
                                            const float* __restrict__ mb1,
                                            const float* __restrict__ mw2,
                                            const float* __restrict__ mb2,
                                            float a0, float a1, float a2,
                                            float* __restrict__ o) {
  const float* w1 = mw1 + M * 48;    // [3][16]
  const float* b1 = mb1 + M * 16;    // [16]
  const float* w2 = mw2 + M * 512;   // [16][32]
  const float* b2 = mb2 + M * 32;    // [32]
  float h[16];
#pragma unroll
  for (int j = 0; j < 16; j++)
    h[j] = lrelu(b1[j] + a0 * w1[j] + a1 * w1[16 + j] + a2 * w1[32 + j]);
#pragma unroll
  for (int c = 0; c < 32; c++) o[c] = b2[c];
#pragma unroll
  for (int j = 0; j < 16; j++) {
#pragma unroll
    for (int c = 0; c < 32; c++) o[c] += h[j] * w2[j * 32 + c];
  }
}

__global__ __launch_bounds__(256) void point_attn_kernel(
    const float* __restrict__ center,   // [P][1][3]
    const float* __restrict__ other,    // [P][16][3]
    const float* __restrict__ mw1, const float* __restrict__ mb1,
    const float* __restrict__ mw2, const float* __restrict__ mb2,
    const float* __restrict__ ww1, const float* __restrict__ wb1,
    const float* __restrict__ ww2, const float* __restrict__ wb2,
    float* __restrict__ out, int P) {
  __shared__ float red[256 * 33];  // [thread][channel]; slot 255 is a dead slot

  const int t  = threadIdx.x;
  const int pt = t / ROWS;                 // 0..15 (15 is the dead tail thread)
  const int r  = t - pt * ROWS;            // 0..16
  int p = blockIdx.x * PPB + pt;
  p = p < P ? p : P - 1;                   // clamp: keeps addresses valid,
  // garbage results land in dead/unread LDS slots. NO divergent branch.

  const float c0 = center[(size_t)p * 3 + 0];
  const float c1 = center[(size_t)p * 3 + 1];
  const float c2 = center[(size_t)p * 3 + 2];
  // neighbor index: clamp r-1 to [0,15]; r==0 result is overridden by selects
  const int rn = (r > 0 ? r - 1 : 0);
  const float* op = other + ((size_t)p * 16 + rn) * 3;
  const float o0 = op[0], o1 = op[1], o2 = op[2];
  const bool is_center = (r == 0);
  const float x0 = is_center ? c0 : o0;
  const float x1 = is_center ? c1 : o1;
  const float x2 = is_center ? c2 : o2;
  const float f0 = c0 - x0, f1 = c1 - x1, f2 = c2 - x2;  // fea_minus (0 for r==0)

  // pos = mlp5(fea_minus)
  float pos[32];
  mlp_3_16_32<5>(mw1, mb1, mw2, mb2, f0, f1, f2, pos);

  // v = (r==0 ? mlp2(center) : mlp4(x));  vp = v + pos
  float tA[32], tB[32], vp[32];
  mlp_3_16_32<2>(mw1, mb1, mw2, mb2, c0, c1, c2, tA);   // cv
  mlp_3_16_32<4>(mw1, mb1, mw2, mb2, x0, x1, x2, tB);   // ov
#pragma unroll
  for (int c = 0; c < 32; c++) vp[c] = (is_center ? tA[c] : tB[c]) + pos[c];

  // k = (r==0 ? mlp1(center) : mlp3(x))
  mlp_3_16_32<1>(mw1, mb1, mw2, mb2, c0, c1, c2, tA);   // ck
  mlp_3_16_32<3>(mw1, mb1, mw2, mb2, x0, x1, x2, tB);   // ok
#pragma unroll
  for (int c = 0; c < 32; c++) tA[c] = (is_center ? tA[c] : tB[c]);  // k

  // w = q - k + pos
  mlp_3_16_32<0>(mw1, mb1, mw2, mb2, c0, c1, c2, tB);   // q
  float w[32];
#pragma unroll
  for (int c = 0; c < 32; c++) w[c] = tB[c] - tA[c] + pos[c];

  // weight_process: 32 -> 64 (leaky) -> 32; contiguous weight reads
  float h[64];
#pragma unroll
  for (int i = 0; i < 64; i++) h[i] = wb1[i];
#pragma unroll
  for (int c = 0; c < 32; c++) {
#pragma unroll
    for (int i = 0; i < 64; i++) h[i] += w[c] * ww1[c * 64 + i];
  }
#pragma unroll
  for (int i = 0; i < 64; i++) h[i] = lrelu(h[i]);
  float fw[32];
#pragma unroll
  for (int c = 0; c < 32; c++) fw[c] = wb2[c];
#pragma unroll
  for (int i = 0; i < 64; i++) {
#pragma unroll
    for (int c = 0; c < 32; c++) fw[c] += h[i] * ww2[i * 32 + c];
  }

  // softmax over channels (thread-local), times (v+pos)
  float m = fw[0];
#pragma unroll
  for (int c = 1; c < 32; c++) m = fmaxf(m, fw[c]);
  float s = 0.f;
#pragma unroll
  for (int c = 0; c < 32; c++) {
    fw[c] = __expf(fw[c] - m);
    s += fw[c];
  }
  const float inv = 1.f / s;
#pragma unroll
  for (int c = 0; c < 32; c++) red[t * 33 + c] = fw[c] * inv * vp[c];

  __syncthreads();

  // reduce 17 rows per point, write output
  const int nval = min(PPB, P - blockIdx.x * PPB);
  for (int u = t; u < nval * 32; u += 256) {
    const int pp = u >> 5, c = u & 31;
    float acc = 0.f;
#pragma unroll
    for (int rr = 0; rr < ROWS; rr++) acc += red[(pp * ROWS + rr) * 33 + c];
    out[(size_t)(blockIdx.x * PPB + pp) * 32 + c] = acc;
  }
}

extern "C" void kernel_launch(void* const* d_in, const int* in_sizes, int n_in,
                              void* d_out, int out_size, void* d_ws, size_t ws_size,
                              hipStream_t stream) {
  const float* center = (const float*)d_in[0];
  const float* other  = (const float*)d_in[1];
  const int P = in_sizes[0] / 3;
  const int blocks = (P + PPB - 1) / PPB;
  point_attn_kernel<<<blocks, 256, 0, stream>>>(
      center, other,
      (const float*)d_in[2], (const float*)d_in[3],
      (const float*)d_in[4], (const float*)d_in[5],
      (const float*)d_in[6], (const float*)d_in[7],
      (const float*)d_in[8], (const float*)d_in[9],
      (float*)d_out, P);
}

// Round 4
// 353.736 us; speedup vs baseline: 11.1889x; 1.4104x over previous
//
#include <hip/hip_runtime.h>
#include <hip/hip_bf16.h>

// ---------------------------------------------------------------------------
// PointAttentionEncoder1D. Round 4: weight_process (32->64->32, 55% of FMAs)
// moved to bf16 MFMA 16x16x32. Phase 1 (VALU): thread-per-row computes
// w = q-k+pos and vp = v+pos, stages w (bf16) to LDS. Phase 2 (MFMA): each
// wave runs 4 M-tiles of 16 rows through both GEMM layers (LDS transpose of h
// between them, per the verified flash-attn pattern). Phase 3: per-row
// softmax*vp. Phase 4: reduce 17 rows -> out.
// Layouts (guide-verified): A[m=lane&15][k=quad*8+j]; C/D col=lane&15,
// row=quad*4+reg; B[k=quad*8+j][n=lane&15].
// ---------------------------------------------------------------------------

constexpr int PPB  = 15;   // points per block (15*17 = 255 active rows + 1 dead)
constexpr int ROWS = 17;   // K+1

typedef __attribute__((ext_vector_type(8))) short bf8;  // 8 bf16 (4 VGPRs)
typedef __attribute__((ext_vector_type(4))) float f4;

__device__ __forceinline__ float lrelu(float v) { return v > 0.f ? v : 0.01f * v; }
__device__ __forceinline__ unsigned short f2bf(float f) {
  return __builtin_bit_cast(unsigned short, __float2bfloat16(f));
}

struct Smem {
  unsigned short w[256 * 32];   // [row][chan] bf16, stride 32 (b128-aligned rows)
  unsigned short h[4][16 * 72]; // per-wave h scratch [m][hc], stride 72 bf16
  float f[256 * 33];            // fw, then softmax*vp products, stride 33
};

template <int M>
__device__ __forceinline__ void mlp_3_16_32(const float* __restrict__ mw1,
                                            const float* __restrict__ mb1,
                                            const float* __restrict__ mw2,
                                            const float* __restrict__ mb2,
                                            float a0, float a1, float a2,
                                            float* __restrict__ o) {
  const float* w1 = mw1 + M * 48;
  const float* b1 = mb1 + M * 16;
  const float* w2 = mw2 + M * 512;
  const float* b2 = mb2 + M * 32;
  float h[16];
#pragma unroll
  for (int j = 0; j < 16; j++)
    h[j] = lrelu(b1[j] + a0 * w1[j] + a1 * w1[16 + j] + a2 * w1[32 + j]);
#pragma unroll
  for (int c = 0; c < 32; c++) o[c] = b2[c];
#pragma unroll
  for (int j = 0; j < 16; j++) {
#pragma unroll
    for (int c = 0; c < 32; c++) o[c] += h[j] * w2[j * 32 + c];
  }
}

__global__ __launch_bounds__(256, 1) void point_attn_kernel(
    const float* __restrict__ center,   // [P][1][3]
    const float* __restrict__ other,    // [P][16][3]
    const float* __restrict__ mw1, const float* __restrict__ mb1,
    const float* __restrict__ mw2, const float* __restrict__ mb2,
    const float* __restrict__ ww1, const float* __restrict__ wb1,
    const float* __restrict__ ww2, const float* __restrict__ wb2,
    float* __restrict__ out, int P) {
  __shared__ Smem sm;

  const int t  = threadIdx.x;
  const int pt = t / ROWS;                 // 0..15 (15 = dead tail thread)
  const int r  = t - pt * ROWS;            // 0..16
  int p = blockIdx.x * PPB + pt;
  p = p < P ? p : P - 1;                   // clamp; garbage lands in dead slots

  // ---------------- Phase 1: per-row VALU MLPs -> w[32], vp[32] -------------
  const float c0 = center[(size_t)p * 3 + 0];
  const float c1 = center[(size_t)p * 3 + 1];
  const float c2 = center[(size_t)p * 3 + 2];
  const int rn = (r > 0 ? r - 1 : 0);
  const float* op = other + ((size_t)p * 16 + rn) * 3;
  const float o0 = op[0], o1 = op[1], o2 = op[2];
  const bool is_center = (r == 0);
  const float x0 = is_center ? c0 : o0;
  const float x1 = is_center ? c1 : o1;
  const float x2 = is_center ? c2 : o2;
  const float f0 = c0 - x0, f1 = c1 - x1, f2 = c2 - x2;

  float pos[32];
  mlp_3_16_32<5>(mw1, mb1, mw2, mb2, f0, f1, f2, pos);

  float tA[32], tB[32], vp[32];
  mlp_3_16_32<2>(mw1, mb1, mw2, mb2, c0, c1, c2, tA);   // cv
  mlp_3_16_32<4>(mw1, mb1, mw2, mb2, x0, x1, x2, tB);   // ov
#pragma unroll
  for (int c = 0; c < 32; c++) vp[c] = (is_center ? tA[c] : tB[c]) + pos[c];

  mlp_3_16_32<1>(mw1, mb1, mw2, mb2, c0, c1, c2, tA);   // ck
  mlp_3_16_32<3>(mw1, mb1, mw2, mb2, x0, x1, x2, tB);   // ok
#pragma unroll
  for (int c = 0; c < 32; c++) tA[c] = (is_center ? tA[c] : tB[c]);  // k

  mlp_3_16_32<0>(mw1, mb1, mw2, mb2, c0, c1, c2, tB);   // q

  // w = q - k + pos, staged to LDS as bf16 (row-major, stride 32)
  {
    unsigned int* dw = (unsigned int*)&sm.w[t * 32];
#pragma unroll
    for (int i = 0; i < 16; i++) {
      const float w0 = tB[2 * i + 0] - tA[2 * i + 0] + pos[2 * i + 0];
      const float w1v = tB[2 * i + 1] - tA[2 * i + 1] + pos[2 * i + 1];
      dw[i] = (unsigned int)f2bf(w0) | ((unsigned int)f2bf(w1v) << 16);
    }
  }
  __syncthreads();

  // ---------------- Phase 2: MFMA weight_process ----------------------------
  const int lane = t & 63, wv = t >> 6;
  const int q = lane >> 4, l = lane & 15;

  // B fragments (wave-invariant weights, bf16) + bias slices
  bf8 B1[4]; float b1v[4];
#pragma unroll
  for (int nt = 0; nt < 4; nt++) {
#pragma unroll
    for (int j = 0; j < 8; j++)
      B1[nt][j] = (short)f2bf(ww1[(q * 8 + j) * 64 + l + 16 * nt]);
    b1v[nt] = wb1[l + 16 * nt];
  }
  bf8 B2[2][2]; float b2v[2];
#pragma unroll
  for (int n2 = 0; n2 < 2; n2++) {
#pragma unroll
    for (int ks = 0; ks < 2; ks++)
#pragma unroll
      for (int j = 0; j < 8; j++)
        B2[n2][ks][j] = (short)f2bf(ww2[(ks * 32 + q * 8 + j) * 32 + l + 16 * n2]);
    b2v[n2] = wb2[l + 16 * n2];
  }

  unsigned short* hb = &sm.h[wv][0];
#pragma unroll
  for (int i = 0; i < 4; i++) {
    const int mt = wv * 4 + i;                    // this wave's M-tile
    // layer 1: [16 rows x 32] x [32 x 64]
    const bf8 a1 = *(const bf8*)&sm.w[(mt * 16 + l) * 32 + q * 8];
    const f4 zero = {0.f, 0.f, 0.f, 0.f};
    f4 c1v[4];
#pragma unroll
    for (int nt = 0; nt < 4; nt++)
      c1v[nt] = __builtin_amdgcn_mfma_f32_16x16x32_bf16(a1, B1[nt], zero, 0, 0, 0);
    // bias + leaky, transpose via LDS (C-layout -> A-layout)
#pragma unroll
    for (int nt = 0; nt < 4; nt++)
#pragma unroll
      for (int rg = 0; rg < 4; rg++)
        hb[(q * 4 + rg) * 72 + l + 16 * nt] = f2bf(lrelu(c1v[nt][rg] + b1v[nt]));
    // layer 2: [16 x 64] x [64 x 32]
    const bf8 a2_0 = *(const bf8*)&hb[l * 72 + 0 + q * 8];
    const bf8 a2_1 = *(const bf8*)&hb[l * 72 + 32 + q * 8];
#pragma unroll
    for (int n2 = 0; n2 < 2; n2++) {
      f4 c2 = __builtin_amdgcn_mfma_f32_16x16x32_bf16(a2_0, B2[n2][0], zero, 0, 0, 0);
      c2 = __builtin_amdgcn_mfma_f32_16x16x32_bf16(a2_1, B2[n2][1], c2, 0, 0, 0);
#pragma unroll
      for (int rg = 0; rg < 4; rg++)
        sm.f[(mt * 16 + q * 4 + rg) * 33 + l + 16 * n2] = c2[rg] + b2v[n2];
    }
  }
  __syncthreads();

  // ---------------- Phase 3: per-row softmax * vp ---------------------------
  float fw[32];
#pragma unroll
  for (int c = 0; c < 32; c++) fw[c] = sm.f[t * 33 + c];
  float m = fw[0];
#pragma unroll
  for (int c = 1; c < 32; c++) m = fmaxf(m, fw[c]);
  float s = 0.f;
#pragma unroll
  for (int c = 0; c < 32; c++) {
    fw[c] = __expf(fw[c] - m);
    s += fw[c];
  }
  const float inv = 1.f / s;
#pragma unroll
  for (int c = 0; c < 32; c++) sm.f[t * 33 + c] = fw[c] * inv * vp[c];
  __syncthreads();

  // ---------------- Phase 4: reduce 17 rows per point -----------------------
  const int nval = min(PPB, P - blockIdx.x * PPB);
  for (int u = t; u < nval * 32; u += 256) {
    const int pp = u >> 5, c = u & 31;
    float acc = 0.f;
#pragma unroll
    for (int rr = 0; rr < ROWS; rr++) acc += sm.f[(pp * ROWS + rr) * 33 + c];
    out[(size_t)(blockIdx.x * PPB + pp) * 32 + c] = acc;
  }
}

extern "C" void kernel_launch(void* const* d_in, const int* in_sizes, int n_in,
                              void* d_out, int out_size, void* d_ws, size_t ws_size,
                              hipStream_t stream) {
  const float* center = (const float*)d_in[0];
  const float* other  = (const float*)d_in[1];
  const int P = in_sizes[0] / 3;
  const int blocks = (P + PPB - 1) / PPB;
  point_attn_kernel<<<blocks, 256, 0, stream>>>(
      center, other,
      (const float*)d_in[2], (const float*)d_in[3],
      (const float*)d_in[4], (const float*)d_in[5],
      (const float*)d_in[6], (const float*)d_in[7],
      (const float*)d_in[8], (const float*)d_in[9],
      (float*)d_out, P);
}

// Round 5
// 203.480 us; speedup vs baseline: 19.4511x; 1.7384x over previous
//
#include <hip/hip_runtime.h>
#include <hip/hip_bf16.h>

// ---------------------------------------------------------------------------
// PointAttentionEncoder1D, Round 5: full-MFMA pipeline.
// Rows per block: [240 other rows (15 pts x 16 nbrs) | 16 center rows].
// S1: [256x32]x[32x64] -> [hk|hv|hp|hq] (biases folded via 1-column).
// S2: [256x64]x[64x64] -> [w | vp] directly (w=q-k+pos, vp=v+pos; signs folded
//     into the virtual weight matrix). Center tiles use a second weight set.
// S3/S4: weight_process 32->64->32 (R4-verified MFMA plumbing).
// Virtual weight matrices are built ONCE per launch by a prep kernel into d_ws
// in per-lane fragment order (one dwordx4 per fragment per lane).
// No __syncthreads until the final cross-point reduce: all LDS reuse is
// wave-private (tile rows == the rows the same wave staged).
// ---------------------------------------------------------------------------

constexpr int PPB = 15;   // points per block

typedef __attribute__((ext_vector_type(8))) short bf8;  // 8 bf16
typedef __attribute__((ext_vector_type(4))) float f4;

__device__ __forceinline__ float lrelu(float v) { return v > 0.f ? v : 0.01f * v; }
__device__ __forceinline__ unsigned short f2bf(float f) {
  return __builtin_bit_cast(unsigned short, __float2bfloat16(f));
}
__device__ __forceinline__ float bf2f(unsigned short s) {
  return __builtin_bit_cast(float, ((unsigned int)s) << 16);
}
__device__ __forceinline__ unsigned int pack2(float a, float b) {
  return (unsigned int)f2bf(a) | ((unsigned int)f2bf(b) << 16);
}

// ---------------- prep kernel: build fragment-packed virtual weights --------
// frag f, lane (q=lane>>4, l=lane&15), j=0..7 holds W[k=q*8+j][n = ntile*16+l].
// frags 0..7   : W1 [32x64]   (set 0 = other, set 1 = center), f = s*4+nt
// frags 8..23  : W2 [64x64]   f = 8 + s*8 + nt*2 + kc
// frags 24..27 : WP1 [32x64]  f = 24+nt
// frags 28..31 : WP2 [64x32]  f = 28 + n2*2 + kc
// floats at ws+32768: [bw_o(32)|bvp_o(32)|bw_c(32)|bvp_c(32)]

__device__ float w1v(const float* mw1, const float* mb1, int s, int k, int n) {
  const int cb = n >> 4, cc = n & 15;
  const int sk = s ? 1 : 3, sv = s ? 2 : 4;
  if (k < 3)  return cb == 0 ? mw1[sk * 48 + k * 16 + cc]
                   : (cb == 1 ? mw1[sv * 48 + k * 16 + cc] : 0.f);
  if (k < 6)  return cb == 2 ? mw1[5 * 48 + (k - 3) * 16 + cc] : 0.f;
  if (k < 9)  return cb == 3 ? mw1[0 * 48 + (k - 6) * 16 + cc] : 0.f;
  if (k == 9) {
    const int m = (cb == 0) ? sk : (cb == 1) ? sv : (cb == 2) ? 5 : 0;
    return mb1[m * 16 + cc];
  }
  return 0.f;
}
__device__ float w2v(const float* mw2, int s, int k, int n) {
  const int sk = s ? 1 : 3, sv = s ? 2 : 4;
  if (n < 32) {  // w = q - k + pos
    if (k < 16)            return -mw2[sk * 512 + k * 32 + n];
    if (k >= 32 && k < 48) return  mw2[5 * 512 + (k - 32) * 32 + n];
    if (k >= 48)           return  mw2[0 * 512 + (k - 48) * 32 + n];
    return 0.f;
  } else {       // vp = v + pos
    const int cc = n - 32;
    if (k >= 16 && k < 32) return mw2[sv * 512 + (k - 16) * 32 + cc];
    if (k >= 32 && k < 48) return mw2[5 * 512 + (k - 32) * 32 + cc];
    return 0.f;
  }
}

__global__ void prep_kernel(const float* __restrict__ mw1, const float* __restrict__ mb1,
                            const float* __restrict__ mw2, const float* __restrict__ mb2,
                            const float* __restrict__ ww1, const float* __restrict__ ww2,
                            unsigned short* __restrict__ ws16, float* __restrict__ wsf) {
  const int tid = blockIdx.x * 256 + threadIdx.x;
  if (tid < 2048) {
    const int f = tid >> 6, lane = tid & 63, q = lane >> 4, l = lane & 15;
    for (int j = 0; j < 8; j++) {
      float v;
      if (f < 8) {
        const int s = f >> 2, nt = f & 3;
        v = w1v(mw1, mb1, s, q * 8 + j, nt * 16 + l);
      } else if (f < 24) {
        const int g = f - 8, s = g >> 3, idx = g & 7, nt = idx >> 1, kc = idx & 1;
        v = w2v(mw2, s, kc * 32 + q * 8 + j, nt * 16 + l);
      } else if (f < 28) {
        const int nt = f - 24;
        v = ww1[(q * 8 + j) * 64 + nt * 16 + l];
      } else {
        const int idx = f - 28, n2 = idx >> 1, kc = idx & 1;
        v = ww2[(kc * 32 + q * 8 + j) * 32 + n2 * 16 + l];
      }
      ws16[f * 512 + lane * 8 + j] = f2bf(v);
    }
  } else if (tid < 2048 + 128) {
    const int t2 = tid - 2048, grp = t2 >> 5, cc = t2 & 31;
    float v;
    if (grp == 0)      v = mb2[cc] - mb2[96 + cc] + mb2[160 + cc];   // bw other
    else if (grp == 1) v = mb2[128 + cc] + mb2[160 + cc];            // bvp other
    else if (grp == 2) v = mb2[cc] - mb2[32 + cc] + mb2[160 + cc];   // bw center
    else               v = mb2[64 + cc] + mb2[160 + cc];             // bvp center
    wsf[grp * 32 + cc] = v;
  }
}

// ---------------- main kernel ----------------------------------------------
struct __align__(16) Smem {
  unsigned short A[256 * 40];   // input A1 -> w -> fw      (stride 40: 2-way)
  unsigned short H[256 * 72];   // h -> hwp                 (stride 72: 2-way)
  unsigned short VP[256 * 40];  // vp -> products
};

__global__ __launch_bounds__(256, 2) void point_attn_kernel(
    const float* __restrict__ center, const float* __restrict__ other,
    const float* __restrict__ wb1, const float* __restrict__ wb2,
    const unsigned short* __restrict__ ws16, const float* __restrict__ wsf,
    float* __restrict__ out, int P) {
  __shared__ Smem sm;
  const int t = threadIdx.x;
  const int lane = t & 63, wv = t >> 6;
  const int q = lane >> 4, l = lane & 15;
  const f4 zero = {0.f, 0.f, 0.f, 0.f};
  const bf8* frag = (const bf8*)ws16;

  // ---- P0: stage input rows. Row t: t<240 -> other (pt=t/16, nbr=t&15);
  //      t>=240 -> center (pt=t-240). Slots [x(3)|fea(3)|c(3)|1|0..].
  {
    int p = (t < 240) ? blockIdx.x * PPB + (t >> 4) : blockIdx.x * PPB + (t - 240);
    p = p < P ? p : P - 1;
    const float c0 = center[(size_t)p * 3 + 0];
    const float c1 = center[(size_t)p * 3 + 1];
    const float c2 = center[(size_t)p * 3 + 2];
    float x0 = c0, x1 = c1, x2 = c2, g0 = 0.f, g1 = 0.f, g2 = 0.f;
    if (t < 240) {
      const float* op = other + ((size_t)p * 16 + (t & 15)) * 3;
      x0 = op[0]; x1 = op[1]; x2 = op[2];
      g0 = c0 - x0; g1 = c1 - x1; g2 = c2 - x2;
    }
    uint4* base = (uint4*)&sm.A[t * 40];
    uint4 v0, v1;
    v0.x = pack2(x0, x1); v0.y = pack2(x2, g0);
    v0.z = pack2(g1, g2); v0.w = pack2(c0, c1);
    v1.x = pack2(c2, 1.0f); v1.y = 0u; v1.z = 0u; v1.w = 0u;
    const uint4 z4 = {0u, 0u, 0u, 0u};
    base[0] = v0; base[1] = v1; base[2] = z4; base[3] = z4;
  }

  // ---- S1: [256x32]x[32x64] -> h = lrelu(.) -> sm.H  (no barrier: wave-private)
  {
    bf8 W1o[4], W1c[4];
#pragma unroll
    for (int nt = 0; nt < 4; nt++) {
      W1o[nt] = frag[nt * 64 + lane];
      W1c[nt] = frag[(4 + nt) * 64 + lane];
    }
#pragma unroll
    for (int i = 0; i < 4; i++) {
      const int tile = wv * 4 + i;
      const bf8 a = *(const bf8*)&sm.A[(tile * 16 + l) * 40 + q * 8];
      f4 h[4];
      if (tile == 15) {
#pragma unroll
        for (int nt = 0; nt < 4; nt++)
          h[nt] = __builtin_amdgcn_mfma_f32_16x16x32_bf16(a, W1c[nt], zero, 0, 0, 0);
      } else {
#pragma unroll
        for (int nt = 0; nt < 4; nt++)
          h[nt] = __builtin_amdgcn_mfma_f32_16x16x32_bf16(a, W1o[nt], zero, 0, 0, 0);
      }
#pragma unroll
      for (int nt = 0; nt < 4; nt++)
#pragma unroll
        for (int rg = 0; rg < 4; rg++)
          sm.H[(tile * 16 + q * 4 + rg) * 72 + l + 16 * nt] = f2bf(lrelu(h[nt][rg]));
    }
  }

  // ---- S2: [256x64]x[64x64] -> [w | vp]; w->sm.A (bf16), vp->sm.VP (bf16)
  {
    bf8 W2o[8], W2c[8];
#pragma unroll
    for (int idx = 0; idx < 8; idx++) {
      W2o[idx] = frag[(8 + idx) * 64 + lane];
      W2c[idx] = frag[(16 + idx) * 64 + lane];
    }
    float biasO[4], biasC[4];
#pragma unroll
    for (int nt = 0; nt < 4; nt++) {
      const int off = (nt < 2) ? nt * 16 + l : 32 + (nt - 2) * 16 + l;
      biasO[nt] = wsf[off];
      biasC[nt] = wsf[64 + off];
    }
#pragma unroll
    for (int i = 0; i < 4; i++) {
      const int tile = wv * 4 + i;
      const bf8 a0 = *(const bf8*)&sm.H[(tile * 16 + l) * 72 + q * 8];
      const bf8 a1 = *(const bf8*)&sm.H[(tile * 16 + l) * 72 + 32 + q * 8];
#pragma unroll
      for (int nt = 0; nt < 4; nt++) {
        f4 acc;
        if (tile == 15) {
          acc = __builtin_amdgcn_mfma_f32_16x16x32_bf16(a0, W2c[nt * 2], zero, 0, 0, 0);
          acc = __builtin_amdgcn_mfma_f32_16x16x32_bf16(a1, W2c[nt * 2 + 1], acc, 0, 0, 0);
        } else {
          acc = __builtin_amdgcn_mfma_f32_16x16x32_bf16(a0, W2o[nt * 2], zero, 0, 0, 0);
          acc = __builtin_amdgcn_mfma_f32_16x16x32_bf16(a1, W2o[nt * 2 + 1], acc, 0, 0, 0);
        }
        const float bias = (tile == 15) ? biasC[nt] : biasO[nt];
#pragma unroll
        for (int rg = 0; rg < 4; rg++) {
          const float val = acc[rg] + bias;
          const int row = tile * 16 + q * 4 + rg;
          if (nt < 2) sm.A[row * 40 + nt * 16 + l] = f2bf(val);
          else        sm.VP[row * 40 + (nt - 2) * 16 + l] = f2bf(val);
        }
      }
    }
  }

  // ---- S3: WP layer 1: [256x32]x[32x64] -> hwp = lrelu(.) -> sm.H
  {
    bf8 WPa[4];
#pragma unroll
    for (int nt = 0; nt < 4; nt++) WPa[nt] = frag[(24 + nt) * 64 + lane];
    float b1v[4];
#pragma unroll
    for (int nt = 0; nt < 4; nt++) b1v[nt] = wb1[l + 16 * nt];
#pragma unroll
    for (int i = 0; i < 4; i++) {
      const int tile = wv * 4 + i;
      const bf8 a = *(const bf8*)&sm.A[(tile * 16 + l) * 40 + q * 8];
#pragma unroll
      for (int nt = 0; nt < 4; nt++) {
        const f4 acc = __builtin_amdgcn_mfma_f32_16x16x32_bf16(a, WPa[nt], zero, 0, 0, 0);
#pragma unroll
        for (int rg = 0; rg < 4; rg++)
          sm.H[(tile * 16 + q * 4 + rg) * 72 + l + 16 * nt] =
              f2bf(lrelu(acc[rg] + b1v[nt]));
      }
    }
  }

  // ---- S4: WP layer 2: [256x64]x[64x32] -> fw -> sm.A (bf16)
  {
    bf8 WPb[4];
#pragma unroll
    for (int idx = 0; idx < 4; idx++) WPb[idx] = frag[(28 + idx) * 64 + lane];
    float b2v[2];
#pragma unroll
    for (int n2 = 0; n2 < 2; n2++) b2v[n2] = wb2[l + 16 * n2];
#pragma unroll
    for (int i = 0; i < 4; i++) {
      const int tile = wv * 4 + i;
      const bf8 a0 = *(const bf8*)&sm.H[(tile * 16 + l) * 72 + q * 8];
      const bf8 a1 = *(const bf8*)&sm.H[(tile * 16 + l) * 72 + 32 + q * 8];
#pragma unroll
      for (int n2 = 0; n2 < 2; n2++) {
        f4 acc = __builtin_amdgcn_mfma_f32_16x16x32_bf16(a0, WPb[n2 * 2], zero, 0, 0, 0);
        acc = __builtin_amdgcn_mfma_f32_16x16x32_bf16(a1, WPb[n2 * 2 + 1], acc, 0, 0, 0);
#pragma unroll
        for (int rg = 0; rg < 4; rg++)
          sm.A[(tile * 16 + q * 4 + rg) * 40 + l + 16 * n2] = f2bf(acc[rg] + b2v[n2]);
      }
    }
  }

  // ---- P5: per-row softmax(fw) * vp -> products back into sm.VP (bf16)
  {
    float fw[32];
#pragma unroll
    for (int ii = 0; ii < 4; ii++) {
      const bf8 v = *(const bf8*)&sm.A[t * 40 + ii * 8];
#pragma unroll
      for (int j = 0; j < 8; j++) fw[ii * 8 + j] = bf2f((unsigned short)v[j]);
    }
    float m = fw[0];
#pragma unroll
    for (int c = 1; c < 32; c++) m = fmaxf(m, fw[c]);
    float s = 0.f;
#pragma unroll
    for (int c = 0; c < 32; c++) { fw[c] = __expf(fw[c] - m); s += fw[c]; }
    const float inv = 1.f / s;
    float vp[32];
#pragma unroll
    for (int ii = 0; ii < 4; ii++) {
      const bf8 v = *(const bf8*)&sm.VP[t * 40 + ii * 8];
#pragma unroll
      for (int j = 0; j < 8; j++) vp[ii * 8 + j] = bf2f((unsigned short)v[j]);
    }
    uint4* dst = (uint4*)&sm.VP[t * 40];
    uint4 o[2];
#pragma unroll
    for (int ii = 0; ii < 2; ii++) {
#pragma unroll
      for (int jj = 0; jj < 4; jj++) {
        const int c = ii * 16 + jj * 4;
        ((unsigned int*)&o[ii])[jj * 2 / 2] = 0;  // placeholder overwritten below
      }
    }
#pragma unroll
    for (int ii = 0; ii < 4; ii++) {
      uint4 w4;
      w4.x = pack2(fw[ii * 8 + 0] * inv * vp[ii * 8 + 0], fw[ii * 8 + 1] * inv * vp[ii * 8 + 1]);
      w4.y = pack2(fw[ii * 8 + 2] * inv * vp[ii * 8 + 2], fw[ii * 8 + 3] * inv * vp[ii * 8 + 3]);
      w4.z = pack2(fw[ii * 8 + 4] * inv * vp[ii * 8 + 4], fw[ii * 8 + 5] * inv * vp[ii * 8 + 5]);
      w4.w = pack2(fw[ii * 8 + 6] * inv * vp[ii * 8 + 6], fw[ii * 8 + 7] * inv * vp[ii * 8 + 7]);
      dst[ii] = w4;
    }
  }

  __syncthreads();

  // ---- P6: reduce 17 rows per point (16 other + 1 center), write out
  for (int u = t; u < 480; u += 256) {
    const int pp = u >> 5, c = u & 31;
    float s = 0.f;
#pragma unroll
    for (int r2 = 0; r2 < 16; r2++) s += bf2f(sm.VP[(pp * 16 + r2) * 40 + c]);
    s += bf2f(sm.VP[(240 + pp) * 40 + c]);
    const int gp = blockIdx.x * PPB + pp;
    if (gp < P) out[(size_t)gp * 32 + c] = s;
  }
}

extern "C" void kernel_launch(void* const* d_in, const int* in_sizes, int n_in,
                              void* d_out, int out_size, void* d_ws, size_t ws_size,
                              hipStream_t stream) {
  const float* center = (const float*)d_in[0];
  const float* other  = (const float*)d_in[1];
  unsigned short* ws16 = (unsigned short*)d_ws;
  float* wsf = (float*)((char*)d_ws + 32768);

  prep_kernel<<<9, 256, 0, stream>>>(
      (const float*)d_in[2], (const float*)d_in[3],
      (const float*)d_in[4], (const float*)d_in[5],
      (const float*)d_in[6], (const float*)d_in[8], ws16, wsf);

  const int P = in_sizes[0] / 3;
  const int blocks = (P + PPB - 1) / PPB;
  point_attn_kernel<<<blocks, 256, 0, stream>>>(
      center, other,
      (const float*)d_in[7], (const float*)d_in[9],
      ws16, wsf, (float*)d_out, P);
}

// Round 6
// 198.608 us; speedup vs baseline: 19.9282x; 1.0245x over previous
//
#include <hip/hip_runtime.h>
#include <hip/hip_bf16.h>

// ---------------------------------------------------------------------------
// PointAttentionEncoder1D, Round 6: transpose-free all-register MFMA chain.
// All GEMMs computed as D = W^T (A-operand, prepacked in d_ws) x X^T (B-op).
// For 16x16 shapes, MFMA C/D layout (row=q*4+reg, col=l) == B-operand layout
// of K=16 MFMA (k=q*4+j, n=l), so each stage's output feeds the next stage's
// B operand in registers. Input B-frags via __shfl from the wave's own staged
// rows. Softmax over channels = 2 shfl_xor (over q); row-sum = 4-step
// butterfly (over l). LDS: only a 2.3KB center-products buffer + 1 barrier.
// ---------------------------------------------------------------------------

constexpr int PPB = 15;

typedef __attribute__((ext_vector_type(8))) short bf8;   // K32 A/B frag
typedef __attribute__((ext_vector_type(4))) short bf4;   // K16 A/B frag
typedef __attribute__((ext_vector_type(4))) float f4;

__device__ __forceinline__ float lrelu(float v) { return v > 0.f ? v : 0.01f * v; }
__device__ __forceinline__ unsigned short f2bf(float f) {
  return __builtin_bit_cast(unsigned short, __float2bfloat16(f));
}
__device__ __forceinline__ float bf2f_lo(unsigned int u) {
  return __builtin_bit_cast(float, u << 16);
}
__device__ __forceinline__ float bf2f_hi(unsigned int u) {
  return __builtin_bit_cast(float, u & 0xffff0000u);
}
__device__ __forceinline__ unsigned int pack2(float a, float b) {
  return (unsigned int)f2bf(a) | ((unsigned int)f2bf(b) << 16);
}

__device__ __forceinline__ f4 mfma16(bf4 a, bf4 b, f4 c) {
#if __has_builtin(__builtin_amdgcn_mfma_f32_16x16x16_bf16)
  return __builtin_amdgcn_mfma_f32_16x16x16_bf16(a, b, c, 0, 0, 0);
#elif __has_builtin(__builtin_amdgcn_mfma_f32_16x16x16bf16_1k)
  return __builtin_amdgcn_mfma_f32_16x16x16bf16_1k(a, b, c, 0, 0, 0);
#else
  f4 d;
  asm volatile("v_mfma_f32_16x16x16_bf16 %0, %1, %2, %3"
               : "=&v"(d) : "v"(a), "v"(b), "v"(c));
  return d;
#endif
}

// ---------------- virtual weight matrices (same math as R5) -----------------
__device__ float w1v(const float* mw1, const float* mb1, int s, int k, int n) {
  const int cb = n >> 4, cc = n & 15;
  const int sk = s ? 1 : 3, sv = s ? 2 : 4;
  if (k < 3)  return cb == 0 ? mw1[sk * 48 + k * 16 + cc]
                   : (cb == 1 ? mw1[sv * 48 + k * 16 + cc] : 0.f);
  if (k < 6)  return cb == 2 ? mw1[5 * 48 + (k - 3) * 16 + cc] : 0.f;
  if (k < 9)  return cb == 3 ? mw1[0 * 48 + (k - 6) * 16 + cc] : 0.f;
  if (k == 9) {
    const int m = (cb == 0) ? sk : (cb == 1) ? sv : (cb == 2) ? 5 : 0;
    return mb1[m * 16 + cc];
  }
  return 0.f;
}
__device__ float w2v(const float* mw2, int s, int k, int n) {
  const int sk = s ? 1 : 3, sv = s ? 2 : 4;
  if (n < 32) {  // w = q - k + pos
    if (k < 16)            return -mw2[sk * 512 + k * 32 + n];
    if (k >= 32 && k < 48) return  mw2[5 * 512 + (k - 32) * 32 + n];
    if (k >= 48)           return  mw2[0 * 512 + (k - 48) * 32 + n];
    return 0.f;
  } else {       // vp = v + pos
    const int cc = n - 32;
    if (k >= 16 && k < 32) return mw2[sv * 512 + (k - 16) * 32 + cc];
    if (k >= 32 && k < 48) return mw2[5 * 512 + (k - 32) * 32 + cc];
    return 0.f;
  }
}

// ws16 layout (shorts):
//  [0,4096)      W1^T  8 K32-frags: f=s*4+c          val = w1v(s, q*8+j, c*16+l)
//  [4096,12288)  W2^T 32 K16-frags: f=s*16+mc*4+kc   val = w2v(s, kc*16+q*4+j, mc*16+l)
//  [12288,14336) WP1^T 8 K16-frags: f=mc*2+kc        val = ww1[(kc*16+q*4+j)*64+mc*16+l]
//  [14336,16384) WP2^T 8 K16-frags: f=mc*4+kc        val = ww2[(kc*16+q*4+j)*32+mc*16+l]
// wsf (floats @ byte 32768): [bw_o(32)|bvp_o(32)|bw_c(32)|bvp_c(32)]
__global__ void prep_kernel(const float* __restrict__ mw1, const float* __restrict__ mb1,
                            const float* __restrict__ mw2, const float* __restrict__ mb2,
                            const float* __restrict__ ww1, const float* __restrict__ ww2,
                            unsigned short* __restrict__ ws16, float* __restrict__ wsf) {
  const int tid = blockIdx.x * 256 + threadIdx.x;
  const int lane = tid & 63, q = lane >> 4, l = lane & 15;
  if (tid < 512) {
    const int f = tid >> 6, s = f >> 2, c = f & 3;
    for (int j = 0; j < 8; j++)
      ws16[f * 512 + lane * 8 + j] = f2bf(w1v(mw1, mb1, s, q * 8 + j, c * 16 + l));
  } else if (tid < 2560) {
    const int f = (tid - 512) >> 6, s = f >> 4, mc = (f >> 2) & 3, kc = f & 3;
    for (int j = 0; j < 4; j++)
      ws16[4096 + f * 256 + lane * 4 + j] = f2bf(w2v(mw2, s, kc * 16 + q * 4 + j, mc * 16 + l));
  } else if (tid < 3072) {
    const int f = (tid - 2560) >> 6, mc = f >> 1, kc = f & 1;
    for (int j = 0; j < 4; j++)
      ws16[12288 + f * 256 + lane * 4 + j] = f2bf(ww1[(kc * 16 + q * 4 + j) * 64 + mc * 16 + l]);
  } else if (tid < 3584) {
    const int f = (tid - 3072) >> 6, mc = f >> 2, kc = f & 3;
    for (int j = 0; j < 4; j++)
      ws16[14336 + f * 256 + lane * 4 + j] = f2bf(ww2[(kc * 16 + q * 4 + j) * 32 + mc * 16 + l]);
  } else if (tid < 3712) {
    const int t2 = tid - 3584, grp = t2 >> 5, cc = t2 & 31;
    float v;
    if (grp == 0)      v = mb2[cc] - mb2[96 + cc] + mb2[160 + cc];   // bw other
    else if (grp == 1) v = mb2[128 + cc] + mb2[160 + cc];            // bvp other
    else if (grp == 2) v = mb2[cc] - mb2[32 + cc] + mb2[160 + cc];   // bw center
    else               v = mb2[64 + cc] + mb2[160 + cc];             // bvp center
    wsf[grp * 32 + cc] = v;
  }
}

// ---------------- main kernel ----------------------------------------------
__global__ __launch_bounds__(256, 3) void point_attn_kernel(
    const float* __restrict__ center, const float* __restrict__ other,
    const float* __restrict__ wb1, const float* __restrict__ wb2,
    const unsigned short* __restrict__ ws16, const float* __restrict__ wsf,
    float* __restrict__ out, int P) {
  __shared__ float cb[16 * 36 + 4];  // center products [row l][ch], stride 36

  const int t = threadIdx.x, lane = t & 63, wv = t >> 6;
  const int q = lane >> 4, l = lane & 15;
  const f4 fzero = {0.f, 0.f, 0.f, 0.f};

  // ---- stage this thread's row into registers (row r = t) ----
  unsigned int d0, d1, d2, d3, d4;
  {
    const int isC = (t >= 240);
    const int pt = isC ? (t - 240) : (t >> 4);
    int p = blockIdx.x * PPB + pt;
    p = p < P ? p : P - 1;
    const float c0 = center[(size_t)p * 3 + 0];
    const float c1 = center[(size_t)p * 3 + 1];
    const float c2 = center[(size_t)p * 3 + 2];
    const float* op = other + ((size_t)p * 16 + (t & 15)) * 3;
    const float o0 = op[0], o1 = op[1], o2 = op[2];
    const float x0 = isC ? c0 : o0, x1 = isC ? c1 : o1, x2 = isC ? c2 : o2;
    const float g0 = c0 - x0, g1 = c1 - x1, g2 = c2 - x2;  // 0 for center rows
    d0 = pack2(x0, x1); d1 = pack2(x2, g0); d2 = pack2(g1, g2);
    d3 = pack2(c0, c1); d4 = pack2(c2, 1.0f);
  }

  // ---- weight/bias registers ----
  bf8 W1[4]; bf4 W2[4][4]; f4 bw[2], bvp[2];
  bf4 P1[4][2], P2[2][4];
  unsigned int bp1[4][2], bp2[2][2];

  auto loadSet = [&](int s) {
#pragma unroll
    for (int c = 0; c < 4; c++)
      W1[c] = *(const bf8*)(ws16 + ((s * 4 + c) * 64 + lane) * 8);
#pragma unroll
    for (int mc = 0; mc < 4; mc++)
#pragma unroll
      for (int kc = 0; kc < 4; kc++)
        W2[mc][kc] = *(const bf4*)(ws16 + 4096 + ((s * 16 + mc * 4 + kc) * 64 + lane) * 4);
#pragma unroll
    for (int mc = 0; mc < 2; mc++) {
      bw[mc]  = *(const f4*)(wsf + s * 64 + mc * 16 + q * 4);
      bvp[mc] = *(const f4*)(wsf + s * 64 + 32 + mc * 16 + q * 4);
    }
  };

  loadSet(wv == 3 ? 1 : 0);
#pragma unroll
  for (int mc = 0; mc < 4; mc++)
#pragma unroll
    for (int kc = 0; kc < 2; kc++)
      P1[mc][kc] = *(const bf4*)(ws16 + 12288 + ((mc * 2 + kc) * 64 + lane) * 4);
#pragma unroll
  for (int mc = 0; mc < 2; mc++)
#pragma unroll
    for (int kc = 0; kc < 4; kc++)
      P2[mc][kc] = *(const bf4*)(ws16 + 14336 + ((mc * 4 + kc) * 64 + lane) * 4);
#pragma unroll
  for (int mc = 0; mc < 4; mc++) {
    const f4 b = *(const f4*)(wb1 + mc * 16 + q * 4);
    bp1[mc][0] = pack2(b[0], b[1]); bp1[mc][1] = pack2(b[2], b[3]);
  }
#pragma unroll
  for (int mc = 0; mc < 2; mc++) {
    const f4 b = *(const f4*)(wb2 + mc * 16 + q * 4);
    bp2[mc][0] = pack2(b[0], b[1]); bp2[mc][1] = pack2(b[2], b[3]);
  }

  auto computeTile = [&](int T, float (&pout)[2][4]) {
    const int src = ((T & 3) << 4) | l;
    const unsigned int s0 = __shfl((int)d0, src), s1 = __shfl((int)d1, src),
                       s2 = __shfl((int)d2, src), s3 = __shfl((int)d3, src),
                       s4 = __shfl((int)d4, src);
    uint4 bu;
    bu.x = q == 0 ? s0 : (q == 1 ? s4 : 0u);
    bu.y = q == 0 ? s1 : 0u;
    bu.z = q == 0 ? s2 : 0u;
    bu.w = q == 0 ? s3 : 0u;
    const bf8 bx = __builtin_bit_cast(bf8, bu);

    // S1: H^T chunks (K=32)
    bf4 hB[4];
#pragma unroll
    for (int c = 0; c < 4; c++) {
      const f4 D1 = __builtin_amdgcn_mfma_f32_16x16x32_bf16(W1[c], bx, fzero, 0, 0, 0);
#pragma unroll
      for (int j = 0; j < 4; j++) hB[c][j] = (short)f2bf(lrelu(D1[j]));
    }

    // S2: [w|vp]^T = W2^T x H^T
    bf4 wB[2]; float vpv[2][4];
#pragma unroll
    for (int mc = 0; mc < 4; mc++) {
      f4 acc = fzero;
#pragma unroll
      for (int kc = 0; kc < 4; kc++) acc = mfma16(W2[mc][kc], hB[kc], acc);
      if (mc < 2) {
#pragma unroll
        for (int j = 0; j < 4; j++) wB[mc][j] = (short)f2bf(acc[j] + bw[mc][j]);
      } else {
#pragma unroll
        for (int j = 0; j < 4; j++) vpv[mc - 2][j] = acc[j] + bvp[mc - 2][j];
      }
    }

    // S3: Hwp^T = WP1^T x w^T
    bf4 h2B[4];
#pragma unroll
    for (int mc = 0; mc < 4; mc++) {
      f4 acc = fzero;
#pragma unroll
      for (int kc = 0; kc < 2; kc++) acc = mfma16(P1[mc][kc], wB[kc], acc);
#pragma unroll
      for (int j = 0; j < 4; j++) {
        const unsigned int bp = bp1[mc][j >> 1];
        const float b = (j & 1) ? bf2f_hi(bp) : bf2f_lo(bp);
        h2B[mc][j] = (short)f2bf(lrelu(acc[j] + b));
      }
    }

    // S4: fw^T = WP2^T x Hwp^T
    float fw[2][4];
#pragma unroll
    for (int mc = 0; mc < 2; mc++) {
      f4 acc = fzero;
#pragma unroll
      for (int kc = 0; kc < 4; kc++) acc = mfma16(P2[mc][kc], h2B[kc], acc);
#pragma unroll
      for (int j = 0; j < 4; j++) {
        const unsigned int bp = bp2[mc][j >> 1];
        fw[mc][j] = acc[j] + ((j & 1) ? bf2f_hi(bp) : bf2f_lo(bp));
      }
    }

    // softmax over the 32 channels of row l (8 local values + cross-q)
    float mx = fw[0][0];
#pragma unroll
    for (int mc = 0; mc < 2; mc++)
#pragma unroll
      for (int j = 0; j < 4; j++) mx = fmaxf(mx, fw[mc][j]);
    mx = fmaxf(mx, __shfl_xor(mx, 16));
    mx = fmaxf(mx, __shfl_xor(mx, 32));
    float e[2][4], sum = 0.f;
#pragma unroll
    for (int mc = 0; mc < 2; mc++)
#pragma unroll
      for (int j = 0; j < 4; j++) { e[mc][j] = __expf(fw[mc][j] - mx); sum += e[mc][j]; }
    sum += __shfl_xor(sum, 16);
    sum += __shfl_xor(sum, 32);
    const float inv = 1.f / sum;
#pragma unroll
    for (int mc = 0; mc < 2; mc++)
#pragma unroll
      for (int j = 0; j < 4; j++) pout[mc][j] = e[mc][j] * inv * vpv[mc][j];
  };

  auto reduceStore = [&](int T, float (&p)[2][4]) {
#pragma unroll
    for (int st = 1; st <= 8; st <<= 1)
#pragma unroll
      for (int mc = 0; mc < 2; mc++)
#pragma unroll
        for (int j = 0; j < 4; j++) p[mc][j] += __shfl_xor(p[mc][j], st);
    if (l == 0) {
      const int gp = blockIdx.x * PPB + T;
      if (gp < P) {
        const f4 a0 = *(const f4*)&cb[T * 36 + q * 4];
        const f4 a1 = *(const f4*)&cb[T * 36 + 16 + q * 4];
        f4 o0, o1;
#pragma unroll
        for (int j = 0; j < 4; j++) { o0[j] = p[0][j] + a0[j]; o1[j] = p[1][j] + a1[j]; }
        *(f4*)(out + (size_t)gp * 32 + q * 4) = o0;
        *(f4*)(out + (size_t)gp * 32 + 16 + q * 4) = o1;
      }
    }
  };

  // iter 0: wave 3 does the center tile (15) with the center weight set
  const int T0 = (wv == 3) ? 15 : wv * 4;
  float p0[2][4];
  computeTile(T0, p0);
  if (wv == 3) {
    f4 c0v, c1v;
#pragma unroll
    for (int j = 0; j < 4; j++) { c0v[j] = p0[0][j]; c1v[j] = p0[1][j]; }
    *(f4*)&cb[l * 36 + q * 4] = c0v;
    *(f4*)&cb[l * 36 + 16 + q * 4] = c1v;
  }
  __syncthreads();
  if (wv == 3) {
    loadSet(0);                 // switch to the "other" weight set
  } else {
    reduceStore(T0, p0);
  }
#pragma unroll
  for (int jj = 1; jj < 4; jj++) {
    const int T = (wv == 3) ? (11 + jj) : (wv * 4 + jj);
    float p[2][4];
    computeTile(T, p);
    reduceStore(T, p);
  }
}

extern "C" void kernel_launch(void* const* d_in, const int* in_sizes, int n_in,
                              void* d_out, int out_size, void* d_ws, size_t ws_size,
                              hipStream_t stream) {
  const float* center = (const float*)d_in[0];
  const float* other  = (const float*)d_in[1];
  unsigned short* ws16 = (unsigned short*)d_ws;
  float* wsf = (float*)((char*)d_ws + 32768);

  prep_kernel<<<15, 256, 0, stream>>>(
      (const float*)d_in[2], (const float*)d_in[3],
      (const float*)d_in[4], (const float*)d_in[5],
      (const float*)d_in[6], (const float*)d_in[8], ws16, wsf);

  const int P = in_sizes[0] / 3;
  const int blocks = (P + PPB - 1) / PPB;
  point_attn_kernel<<<blocks, 256, 0, stream>>>(
      center, other,
      (const float*)d_in[7], (const float*)d_in[9],
      ws16, wsf, (float*)d_out, P);
}

// Round 7
// 155.184 us; speedup vs baseline: 25.5046x; 1.2798x over previous
//
#include <hip/hip_runtime.h>
#include <hip/hip_bf16.h>

// ---------------------------------------------------------------------------
// PointAttentionEncoder1D, Round 7: R6 transpose-free MFMA chain with the
// VALU fat removed.
//  - bf16 packing via (bits+0x8000)>>16 half-up rounding + v_perm_b32:
//    3 inst per 2 values instead of ~14 (HIP __float2bfloat16 is ~7/value).
//  - row-sum butterfly (256 inst/thread) replaced by LDS product buffer
//    (stride 36: b128 writes hit the 8-dword/bank minimum; reduce reads are
//    2-way aliased = free) + single barrier + coalesced final reduce.
//  - frees ~40 VGPRs -> target: no arch/acc split, no scratch (WRITE_SIZE
//    should fall from 43.6 MB back to ~13 MB).
// ---------------------------------------------------------------------------

constexpr int PPB = 15;

typedef __attribute__((ext_vector_type(8))) short bf8;   // K32 A/B frag
typedef __attribute__((ext_vector_type(4))) short bf4;   // K16 A/B frag
typedef __attribute__((ext_vector_type(4))) float f4;

__device__ __forceinline__ float lrelu(float v) { return v > 0.f ? v : 0.01f * v; }

// fast pack: two f32 -> packed bf16x2, round-half-up (values are finite)
__device__ __forceinline__ unsigned int pkbf(float a, float b) {
  const unsigned int ua = __builtin_bit_cast(unsigned int, a) + 0x8000u;
  const unsigned int ub = __builtin_bit_cast(unsigned int, b) + 0x8000u;
  return __builtin_amdgcn_perm(ub, ua, 0x07060302u);  // [ub.hi16 : ua.hi16]
}
__device__ __forceinline__ bf4 mkbf4(float v0, float v1, float v2, float v3) {
  uint2 u; u.x = pkbf(v0, v1); u.y = pkbf(v2, v3);
  return __builtin_bit_cast(bf4, u);
}
__device__ __forceinline__ float bf2f_lo(unsigned int u) {
  return __builtin_bit_cast(float, u << 16);
}
__device__ __forceinline__ float bf2f_hi(unsigned int u) {
  return __builtin_bit_cast(float, u & 0xffff0000u);
}

__device__ __forceinline__ f4 mfma16(bf4 a, bf4 b, f4 c) {
#if __has_builtin(__builtin_amdgcn_mfma_f32_16x16x16_bf16)
  return __builtin_amdgcn_mfma_f32_16x16x16_bf16(a, b, c, 0, 0, 0);
#elif __has_builtin(__builtin_amdgcn_mfma_f32_16x16x16bf16_1k)
  return __builtin_amdgcn_mfma_f32_16x16x16bf16_1k(a, b, c, 0, 0, 0);
#else
  f4 d;
  asm volatile("v_mfma_f32_16x16x16_bf16 %0, %1, %2, %3"
               : "=&v"(d) : "v"(a), "v"(b), "v"(c));
  return d;
#endif
}

// ---------------- virtual weight matrices (same math as R5/R6) --------------
__device__ float w1v(const float* mw1, const float* mb1, int s, int k, int n) {
  const int cb = n >> 4, cc = n & 15;
  const int sk = s ? 1 : 3, sv = s ? 2 : 4;
  if (k < 3)  return cb == 0 ? mw1[sk * 48 + k * 16 + cc]
                   : (cb == 1 ? mw1[sv * 48 + k * 16 + cc] : 0.f);
  if (k < 6)  return cb == 2 ? mw1[5 * 48 + (k - 3) * 16 + cc] : 0.f;
  if (k < 9)  return cb == 3 ? mw1[0 * 48 + (k - 6) * 16 + cc] : 0.f;
  if (k == 9) {
    const int m = (cb == 0) ? sk : (cb == 1) ? sv : (cb == 2) ? 5 : 0;
    return mb1[m * 16 + cc];
  }
  return 0.f;
}
__device__ float w2v(const float* mw2, int s, int k, int n) {
  const int sk = s ? 1 : 3, sv = s ? 2 : 4;
  if (n < 32) {  // w = q - k + pos
    if (k < 16)            return -mw2[sk * 512 + k * 32 + n];
    if (k >= 32 && k < 48) return  mw2[5 * 512 + (k - 32) * 32 + n];
    if (k >= 48)           return  mw2[0 * 512 + (k - 48) * 32 + n];
    return 0.f;
  } else {       // vp = v + pos
    const int cc = n - 32;
    if (k >= 16 && k < 32) return mw2[sv * 512 + (k - 16) * 32 + cc];
    if (k >= 32 && k < 48) return mw2[5 * 512 + (k - 32) * 32 + cc];
    return 0.f;
  }
}

// ws16 layout (shorts):
//  [0,4096)      W1^T  8 K32-frags: f=s*4+c          val = w1v(s, q*8+j, c*16+l)
//  [4096,12288)  W2^T 32 K16-frags: f=s*16+mc*4+kc   val = w2v(s, kc*16+q*4+j, mc*16+l)
//  [12288,14336) WP1^T 8 K16-frags: f=mc*2+kc        val = ww1[(kc*16+q*4+j)*64+mc*16+l]
//  [14336,16384) WP2^T 8 K16-frags: f=mc*4+kc        val = ww2[(kc*16+q*4+j)*32+mc*16+l]
// wsf (floats @ byte 32768): [bw_o(32)|bvp_o(32)|bw_c(32)|bvp_c(32)]
__global__ void prep_kernel(const float* __restrict__ mw1, const float* __restrict__ mb1,
                            const float* __restrict__ mw2, const float* __restrict__ mb2,
                            const float* __restrict__ ww1, const float* __restrict__ ww2,
                            unsigned short* __restrict__ ws16, float* __restrict__ wsf) {
  const int tid = blockIdx.x * 256 + threadIdx.x;
  const int lane = tid & 63, q = lane >> 4, l = lane & 15;
  if (tid < 512) {
    const int f = tid >> 6, s = f >> 2, c = f & 3;
    for (int j = 0; j < 8; j++)
      ws16[f * 512 + lane * 8 + j] =
          (unsigned short)(pkbf(w1v(mw1, mb1, s, q * 8 + j, c * 16 + l), 0.f) & 0xffffu);
  } else if (tid < 2560) {
    const int f = (tid - 512) >> 6, s = f >> 4, mc = (f >> 2) & 3, kc = f & 3;
    for (int j = 0; j < 4; j++)
      ws16[4096 + f * 256 + lane * 4 + j] =
          (unsigned short)(pkbf(w2v(mw2, s, kc * 16 + q * 4 + j, mc * 16 + l), 0.f) & 0xffffu);
  } else if (tid < 3072) {
    const int f = (tid - 2560) >> 6, mc = f >> 1, kc = f & 1;
    for (int j = 0; j < 4; j++)
      ws16[12288 + f * 256 + lane * 4 + j] =
          (unsigned short)(pkbf(ww1[(kc * 16 + q * 4 + j) * 64 + mc * 16 + l], 0.f) & 0xffffu);
  } else if (tid < 3584) {
    const int f = (tid - 3072) >> 6, mc = f >> 2, kc = f & 3;
    for (int j = 0; j < 4; j++)
      ws16[14336 + f * 256 + lane * 4 + j] =
          (unsigned short)(pkbf(ww2[(kc * 16 + q * 4 + j) * 32 + mc * 16 + l], 0.f) & 0xffffu);
  } else if (tid < 3712) {
    const int t2 = tid - 3584, grp = t2 >> 5, cc = t2 & 31;
    float v;
    if (grp == 0)      v = mb2[cc] - mb2[96 + cc] + mb2[160 + cc];   // bw other
    else if (grp == 1) v = mb2[128 + cc] + mb2[160 + cc];            // bvp other
    else if (grp == 2) v = mb2[cc] - mb2[32 + cc] + mb2[160 + cc];   // bw center
    else               v = mb2[64 + cc] + mb2[160 + cc];             // bvp center
    wsf[grp * 32 + cc] = v;
  }
}

// ---------------- main kernel ----------------------------------------------
__global__ __launch_bounds__(256, 3) void point_attn_kernel(
    const float* __restrict__ center, const float* __restrict__ other,
    const float* __restrict__ wb1, const float* __restrict__ wb2,
    const unsigned short* __restrict__ ws16, const float* __restrict__ wsf,
    float* __restrict__ out, int P) {
  __shared__ float pr[256 * 36];  // products [row][ch], stride 36 dwords

  const int t = threadIdx.x, lane = t & 63, wv = t >> 6;
  const int q = lane >> 4, l = lane & 15;
  const f4 fzero = {0.f, 0.f, 0.f, 0.f};

  // ---- stage this thread's row into registers (row r = t) ----
  unsigned int d0, d1, d2, d3, d4;
  {
    const int isC = (t >= 240);
    const int pt = isC ? (t - 240) : (t >> 4);
    int p = blockIdx.x * PPB + pt;
    p = p < P ? p : P - 1;
    const float c0 = center[(size_t)p * 3 + 0];
    const float c1 = center[(size_t)p * 3 + 1];
    const float c2 = center[(size_t)p * 3 + 2];
    const float* op = other + ((size_t)p * 16 + (t & 15)) * 3;
    const float o0 = op[0], o1 = op[1], o2 = op[2];
    const float x0 = isC ? c0 : o0, x1 = isC ? c1 : o1, x2 = isC ? c2 : o2;
    const float g0 = c0 - x0, g1 = c1 - x1, g2 = c2 - x2;  // 0 for center rows
    d0 = pkbf(x0, x1); d1 = pkbf(x2, g0); d2 = pkbf(g1, g2);
    d3 = pkbf(c0, c1); d4 = pkbf(c2, 1.0f);
  }

  // ---- weight/bias registers ----
  bf8 W1[4]; bf4 W2[4][4]; f4 bw[2], bvp[2];
  bf4 P1[4][2], P2[2][4];
  unsigned int bp1[4][2], bp2[2][2];

  auto loadSet = [&](int s) {
#pragma unroll
    for (int c = 0; c < 4; c++)
      W1[c] = *(const bf8*)(ws16 + ((s * 4 + c) * 64 + lane) * 8);
#pragma unroll
    for (int mc = 0; mc < 4; mc++)
#pragma unroll
      for (int kc = 0; kc < 4; kc++)
        W2[mc][kc] = *(const bf4*)(ws16 + 4096 + ((s * 16 + mc * 4 + kc) * 64 + lane) * 4);
#pragma unroll
    for (int mc = 0; mc < 2; mc++) {
      bw[mc]  = *(const f4*)(wsf + s * 64 + mc * 16 + q * 4);
      bvp[mc] = *(const f4*)(wsf + s * 64 + 32 + mc * 16 + q * 4);
    }
  };

  loadSet(wv == 3 ? 1 : 0);
#pragma unroll
  for (int mc = 0; mc < 4; mc++)
#pragma unroll
    for (int kc = 0; kc < 2; kc++)
      P1[mc][kc] = *(const bf4*)(ws16 + 12288 + ((mc * 2 + kc) * 64 + lane) * 4);
#pragma unroll
  for (int mc = 0; mc < 2; mc++)
#pragma unroll
    for (int kc = 0; kc < 4; kc++)
      P2[mc][kc] = *(const bf4*)(ws16 + 14336 + ((mc * 4 + kc) * 64 + lane) * 4);
#pragma unroll
  for (int mc = 0; mc < 4; mc++) {
    const f4 b = *(const f4*)(wb1 + mc * 16 + q * 4);
    bp1[mc][0] = pkbf(b[0], b[1]); bp1[mc][1] = pkbf(b[2], b[3]);
  }
#pragma unroll
  for (int mc = 0; mc < 2; mc++) {
    const f4 b = *(const f4*)(wb2 + mc * 16 + q * 4);
    bp2[mc][0] = pkbf(b[0], b[1]); bp2[mc][1] = pkbf(b[2], b[3]);
  }

  auto computeTile = [&](int T) {
    const int src = ((T & 3) << 4) | l;
    const unsigned int s0 = __shfl((int)d0, src), s1 = __shfl((int)d1, src),
                       s2 = __shfl((int)d2, src), s3 = __shfl((int)d3, src),
                       s4 = __shfl((int)d4, src);
    uint4 bu;
    bu.x = q == 0 ? s0 : (q == 1 ? s4 : 0u);
    bu.y = q == 0 ? s1 : 0u;
    bu.z = q == 0 ? s2 : 0u;
    bu.w = q == 0 ? s3 : 0u;
    const bf8 bx = __builtin_bit_cast(bf8, bu);

    // S1: H^T chunks (K=32)
    bf4 hB[4];
#pragma unroll
    for (int c = 0; c < 4; c++) {
      const f4 D1 = __builtin_amdgcn_mfma_f32_16x16x32_bf16(W1[c], bx, fzero, 0, 0, 0);
      hB[c] = mkbf4(lrelu(D1[0]), lrelu(D1[1]), lrelu(D1[2]), lrelu(D1[3]));
    }

    // S2: [w|vp]^T = W2^T x H^T
    bf4 wB[2]; float vpv[2][4];
#pragma unroll
    for (int mc = 0; mc < 4; mc++) {
      f4 acc = fzero;
#pragma unroll
      for (int kc = 0; kc < 4; kc++) acc = mfma16(W2[mc][kc], hB[kc], acc);
      if (mc < 2) {
        wB[mc] = mkbf4(acc[0] + bw[mc][0], acc[1] + bw[mc][1],
                       acc[2] + bw[mc][2], acc[3] + bw[mc][3]);
      } else {
#pragma unroll
        for (int j = 0; j < 4; j++) vpv[mc - 2][j] = acc[j] + bvp[mc - 2][j];
      }
    }

    // S3: Hwp^T = WP1^T x w^T
    bf4 h2B[4];
#pragma unroll
    for (int mc = 0; mc < 4; mc++) {
      f4 acc = fzero;
#pragma unroll
      for (int kc = 0; kc < 2; kc++) acc = mfma16(P1[mc][kc], wB[kc], acc);
      h2B[mc] = mkbf4(lrelu(acc[0] + bf2f_lo(bp1[mc][0])),
                      lrelu(acc[1] + bf2f_hi(bp1[mc][0])),
                      lrelu(acc[2] + bf2f_lo(bp1[mc][1])),
                      lrelu(acc[3] + bf2f_hi(bp1[mc][1])));
    }

    // S4: fw^T = WP2^T x Hwp^T
    float fw[2][4];
#pragma unroll
    for (int mc = 0; mc < 2; mc++) {
      f4 acc = fzero;
#pragma unroll
      for (int kc = 0; kc < 4; kc++) acc = mfma16(P2[mc][kc], h2B[kc], acc);
      fw[mc][0] = acc[0] + bf2f_lo(bp2[mc][0]);
      fw[mc][1] = acc[1] + bf2f_hi(bp2[mc][0]);
      fw[mc][2] = acc[2] + bf2f_lo(bp2[mc][1]);
      fw[mc][3] = acc[3] + bf2f_hi(bp2[mc][1]);
    }

    // softmax over the 32 channels of row l (8 local + cross-q via shfl)
    float mx = fw[0][0];
#pragma unroll
    for (int mc = 0; mc < 2; mc++)
#pragma unroll
      for (int j = 0; j < 4; j++) mx = fmaxf(mx, fw[mc][j]);
    mx = fmaxf(mx, __shfl_xor(mx, 16));
    mx = fmaxf(mx, __shfl_xor(mx, 32));
    float e[2][4], sum = 0.f;
#pragma unroll
    for (int mc = 0; mc < 2; mc++)
#pragma unroll
      for (int j = 0; j < 4; j++) { e[mc][j] = __expf(fw[mc][j] - mx); sum += e[mc][j]; }
    sum += __shfl_xor(sum, 16);
    sum += __shfl_xor(sum, 32);
    const float inv = 1.f / sum;

    f4 p0, p1;
#pragma unroll
    for (int j = 0; j < 4; j++) {
      p0[j] = e[0][j] * inv * vpv[0][j];
      p1[j] = e[1][j] * inv * vpv[1][j];
    }
    // products -> LDS (stride 36: b128 writes at the 8-dword/bank minimum)
    *(f4*)&pr[(T * 16 + l) * 36 + q * 4] = p0;
    *(f4*)&pr[(T * 16 + l) * 36 + 16 + q * 4] = p1;
  };

  // wave 3 does the center tile (15) first with the center weight set
  computeTile(wv == 3 ? 15 : wv * 4);
  if (wv == 3) loadSet(0);
  for (int jj = 1; jj < 4; jj++)
    computeTile(wv == 3 ? (11 + jj) : (wv * 4 + jj));

  __syncthreads();

  // final reduce: 17 rows per point (16 other + 1 center), coalesced stores
  for (int u = t; u < 480; u += 256) {
    const int pp = u >> 5, c = u & 31;
    float s = pr[(240 + pp) * 36 + c];
#pragma unroll
    for (int r2 = 0; r2 < 16; r2++) s += pr[(pp * 16 + r2) * 36 + c];
    const int gp = blockIdx.x * PPB + pp;
    if (gp < P) out[(size_t)gp * 32 + c] = s;
  }
}

extern "C" void kernel_launch(void* const* d_in, const int* in_sizes, int n_in,
                              void* d_out, int out_size, void* d_ws, size_t ws_size,
                              hipStream_t stream) {
  const float* center = (const float*)d_in[0];
  const float* other  = (const float*)d_in[1];
  unsigned short* ws16 = (unsigned short*)d_ws;
  float* wsf = (float*)((char*)d_ws + 32768);

  prep_kernel<<<15, 256, 0, stream>>>(
      (const float*)d_in[2], (const float*)d_in[3],
      (const float*)d_in[4], (const float*)d_in[5],
      (const float*)d_in[6], (const float*)d_in[8], ws16, wsf);

  const int P = in_sizes[0] / 3;
  const int blocks = (P + PPB - 1) / PPB;
  point_attn_kernel<<<blocks, 256, 0, stream>>>(
      center, other,
      (const float*)d_in[7], (const float*)d_in[9],
      ws16, wsf, (float*)d_out, P);
}